// Round 4
// baseline (402.859 us; speedup 1.0000x reference)
//
#include <hip/hip_runtime.h>
#include <hip/hip_bf16.h>

#define BB 32
#define NN 1025
#define CC 512
#define HH 8
#define HD 64
#define MM (BB * NN)        // 32800
#define MP2 33024           // 129 * 256 (padded M for 256-tiles)
#define KK 512
#define SCALE 0.125f

typedef unsigned short u16;
typedef __attribute__((ext_vector_type(4))) unsigned short u16x4;
typedef __attribute__((ext_vector_type(8))) unsigned short u16x8;
typedef __attribute__((ext_vector_type(4))) float f32x4;
typedef __attribute__((ext_vector_type(8))) __bf16 bf16x8;

__device__ __forceinline__ u16 f2bf(float f) {
    unsigned u = __float_as_uint(f);
    unsigned r = (u + 0x7FFFu + ((u >> 16) & 1u)) >> 16;
    return (u16)r;
}
__device__ __forceinline__ float bf2f(u16 h) {
    return __uint_as_float((unsigned)h << 16);
}

__device__ __forceinline__ void gload16(const u16* g, u16* l) {
    __builtin_amdgcn_global_load_lds(
        (const __attribute__((address_space(1))) unsigned int*)g,
        (__attribute__((address_space(3))) unsigned int*)l, 16, 0, 0);
}

// ---------------------------------------------------------------------------
// convert x (fp32 [MM][512]) -> xbf (bf16 [MP2][512]), zero pad rows
// ---------------------------------------------------------------------------
__global__ __launch_bounds__(256) void convert_x_kernel(
    const float* __restrict__ x, u16* __restrict__ xbf)
{
    size_t t = (size_t)blockIdx.x * 256 + threadIdx.x;
    size_t base = t * 8;
    u16x8 o;
    if (base < (size_t)MM * CC) {
        f32x4 a = *(const f32x4*)&x[base];
        f32x4 b = *(const f32x4*)&x[base + 4];
#pragma unroll
        for (int j = 0; j < 4; j++) { o[j] = f2bf(a[j]); o[j + 4] = f2bf(b[j]); }
    } else {
#pragma unroll
        for (int j = 0; j < 8; j++) o[j] = 0;
    }
    *(u16x8*)&xbf[base] = o;
}

// ---------------------------------------------------------------------------
// transpose+convert weights: Wt[n][k] = bf16(W[k][n]);  K = 512
// ---------------------------------------------------------------------------
__global__ __launch_bounds__(256) void convert_wt_kernel(
    const float* __restrict__ W, u16* __restrict__ Wt, int N)
{
    int t = blockIdx.x * 256 + threadIdx.x;
    int n = t >> 6;
    int k0 = (t & 63) * 8;
    u16x8 o;
#pragma unroll
    for (int j = 0; j < 8; j++) o[j] = f2bf(W[(size_t)(k0 + j) * N + n]);
    *(u16x8*)&Wt[(size_t)n * KK + k0] = o;
}

// ---------------------------------------------------------------------------
// expand conv weights into dense [7][7][512] table (+ merged bias [512])
// ---------------------------------------------------------------------------
__global__ __launch_bounds__(256) void prep_w7_kernel(
    const float* __restrict__ ck3, const float* __restrict__ cb3,
    const float* __restrict__ ck5, const float* __restrict__ cb5,
    const float* __restrict__ ck7, const float* __restrict__ cb7,
    float* __restrict__ w7, float* __restrict__ cbx)
{
    int t = blockIdx.x * 256 + threadIdx.x;   // 49*512 = 25088
    if (t >= 49 * 512) return;
    int c = t & 511;
    int tap = t >> 9;
    int dy = tap / 7, dx = tap % 7;
    float w = 0.f;
    if (c < 128) {
        int ry = dy - 2, rx = dx - 2;
        if (ry >= 0 && ry < 3 && rx >= 0 && rx < 3) w = ck3[(ry * 3 + rx) * 128 + c];
    } else if (c < 320) {
        int ry = dy - 1, rx = dx - 1;
        if (ry >= 0 && ry < 5 && rx >= 0 && rx < 5) w = ck5[(ry * 5 + rx) * 192 + (c - 128)];
    } else {
        w = ck7[(dy * 7 + dx) * 192 + (c - 320)];
    }
    w7[tap * 512 + c] = w;
    if (t < 512)
        cbx[t] = (t < 128) ? cb3[t] : (t < 320) ? cb5[t - 128] : cb7[t - 320];
}

// ---------------------------------------------------------------------------
// 8-phase 256x256 bf16 MFMA GEMM (T1+T2+T3+T4+T5).
// A [MP2][512] bf16, Bt [N][512] bf16 (row = output col). 512 thr, 8 waves.
// K split into 8 tiles of 64; each tile = 4 phases (kh,ihalf); staging of the
// next tile's 4 K-half units is interleaved 1/phase; vmcnt(4) twice per tile.
// MODE 0: scatter bf16 into contiguous q/k/v planes. MODE 1: fp32 out.
// ---------------------------------------------------------------------------
template <int MODE, int NSZ, int GX>
__global__ __launch_bounds__(512, 2) void gemm8p_kernel(
    const u16* __restrict__ A, const u16* __restrict__ Bt,
    const float* __restrict__ bias, void* __restrict__ outv, int nwg)
{
    __shared__ __align__(16) u16 lds[65536];   // 128 KiB: [buf][A/B][kh][128x? ]

    // ---- XCD-bijective block swizzle (m204): consecutive wg -> same XCD chunk
    int wg = blockIdx.x;
    {
        int q = nwg >> 3, r = nwg & 7;
        int xcd = wg & 7, pos = wg >> 3;
        wg = (xcd < r ? xcd * (q + 1) : r * (q + 1) + (xcd - r) * q) + pos;
    }
    const int m0 = (wg / GX) * 256;
    const int n0 = (wg % GX) * 256;

    const int t = threadIdx.x;

    // ---- staging addresses (per K-half unit: 256 rows x 32k = 16KB linear)
    const int srow = t >> 2;                       // 0..127
    const int sp   = t & 3;                        // dest 16B slot within half
    const int ss   = sp ^ ((srow >> 1) & 3);       // pre-swizzled source slot
    const u16* gA = A  + (size_t)(m0 + srow) * KK + ss * 8;
    const u16* gB = Bt + (size_t)(n0 + srow) * KK + ss * 8;

#define STG(dst, gsrc, tt, kh) do {                                          \
        gload16((gsrc) + (tt) * 64 + (kh) * 32,                              \
                (dst) + (kh) * 8192 + t * 8);                                \
        gload16((gsrc) + 128 * KK + (tt) * 64 + (kh) * 32,                   \
                (dst) + (kh) * 8192 + 4096 + t * 8);                         \
    } while (0)

    // ---- fragment read addresses
    const int l  = t & 63;
    const int w  = t >> 6;
    const int wr = w >> 2;        // 0..1  (M)
    const int wc = w & 3;         // 0..3  (N)
    const int lr = l & 15;
    const int slot = (l >> 4) ^ ((lr >> 1) & 3);
    const int offA0 = (wr * 128 + lr) * 32 + slot * 8;   // u16 units
    const int offB0 = (wc * 64 + lr) * 32 + slot * 8;

    f32x4 acc[8][4] = {};

#define PHASE(cA, cB, kh, ih, doSt, sdst, sg, stt, skh, doVm) do {           \
        bf16x8 a_[4], b_[4];                                                 \
        _Pragma("unroll")                                                    \
        for (int i = 0; i < 4; i++)                                          \
            a_[i] = *(const bf16x8*)&(cA)[(kh) * 8192 + offA0 + (ih) * 2048 + i * 512]; \
        _Pragma("unroll")                                                    \
        for (int j = 0; j < 4; j++)                                          \
            b_[j] = *(const bf16x8*)&(cB)[(kh) * 8192 + offB0 + j * 512];    \
        if (doSt) STG(sdst, sg, stt, skh);                                   \
        __builtin_amdgcn_sched_barrier(0);                                   \
        __builtin_amdgcn_s_barrier();                                        \
        __builtin_amdgcn_s_setprio(1);                                       \
        _Pragma("unroll")                                                    \
        for (int i = 0; i < 4; i++)                                          \
            _Pragma("unroll")                                                \
            for (int j = 0; j < 4; j++)                                      \
                acc[(ih) * 4 + i][j] = __builtin_amdgcn_mfma_f32_16x16x32_bf16( \
                    a_[i], b_[j], acc[(ih) * 4 + i][j], 0, 0, 0);            \
        __builtin_amdgcn_s_setprio(0);                                       \
        if (doVm) asm volatile("s_waitcnt vmcnt(4)" ::: "memory");           \
        __builtin_amdgcn_sched_barrier(0);                                   \
        __builtin_amdgcn_s_barrier();                                        \
        __builtin_amdgcn_sched_barrier(0);                                   \
    } while (0)

    // ---- prologue: stage tile0 fully; wait first two halves
    {
        u16* bA = lds;            // buf0 A
        u16* bB = lds + 16384;    // buf0 B
        STG(bA, gA, 0, 0);
        STG(bB, gB, 0, 0);
        STG(bA, gA, 0, 1);
        STG(bB, gB, 0, 1);
    }
    asm volatile("s_waitcnt vmcnt(4)" ::: "memory");
    __builtin_amdgcn_s_barrier();
    __builtin_amdgcn_sched_barrier(0);

    // ---- main loop: 8 K-tiles x 4 phases
    for (int tt = 0; tt < 8; ++tt) {
        u16* cA = lds + (tt & 1) * 32768;
        u16* cB = cA + 16384;
        u16* nA = lds + ((tt + 1) & 1) * 32768;
        u16* nB = nA + 16384;
        const bool st = tt < 7;
        PHASE(cA, cB, 0, 0, st, nA, gA, tt + 1, 0, false);
        PHASE(cA, cB, 0, 1, st, nB, gB, tt + 1, 0, true);   // A_k1,B_k1(tt) ready
        PHASE(cA, cB, 1, 0, st, nA, gA, tt + 1, 1, false);
        PHASE(cA, cB, 1, 1, st, nB, gB, tt + 1, 1, true);   // A_k0,B_k0(tt+1) ready
    }
#undef PHASE
#undef STG

    // ---- epilogue
    const int row0 = m0 + wr * 128 + (l >> 4) * 4;
    const int col0 = n0 + wc * 64 + lr;
    float bs[4];
#pragma unroll
    for (int j = 0; j < 4; j++) bs[j] = bias[col0 + j * 16];

    if (MODE == 0) {
        u16* qkv = (u16*)outv;
        const int plane = n0 >> 9;
        const int cb0 = (n0 & 511) + wc * 64 + lr;
        u16* pl = qkv + (size_t)plane * ((size_t)MP2 * CC);
#pragma unroll
        for (int ii = 0; ii < 8; ii++) {
#pragma unroll
            for (int j = 0; j < 4; j++) {
#pragma unroll
                for (int r = 0; r < 4; r++) {
                    int gm = row0 + ii * 16 + r;
                    pl[(size_t)gm * CC + cb0 + j * 16] = f2bf(acc[ii][j][r] + bs[j]);
                }
            }
        }
    } else {
        float* out = (float*)outv;
#pragma unroll
        for (int ii = 0; ii < 8; ii++) {
#pragma unroll
            for (int j = 0; j < 4; j++) {
#pragma unroll
                for (int r = 0; r < 4; r++) {
                    int gm = row0 + ii * 16 + r;
                    if (gm < MM) out[(size_t)gm * NSZ + col0 + j * 16] = acc[ii][j][r] + bs[j];
                }
            }
        }
    }
}

// ---------------------------------------------------------------------------
// softmax stats over N per (b,c): 8 N-chunks, then merge
// ---------------------------------------------------------------------------
__global__ __launch_bounds__(256) void stats_part_kernel(
    const u16* __restrict__ kbf, float* __restrict__ pmax, float* __restrict__ psum)
{
    int c  = blockIdx.x * 256 + threadIdx.x;
    int b  = blockIdx.y;
    int ch = blockIdx.z;
    int n0 = ch * 128, n1 = (ch == 7) ? NN : n0 + 128;
    const u16* col = kbf + (size_t)(b * NN + n0) * CC + c;
    float m = -1e30f, sum = 0.f;
    for (int n = n0; n < n1; n++, col += CC) {
        float val = bf2f(*col);
        float nm = fmaxf(m, val);
        sum = sum * __expf(m - nm) + __expf(val - nm);
        m = nm;
    }
    pmax[(ch * BB + b) * CC + c] = m;
    psum[(ch * BB + b) * CC + c] = sum;
}

__global__ __launch_bounds__(256) void stats_merge_kernel(
    const float* __restrict__ pmax, const float* __restrict__ psum,
    float* __restrict__ colmax, float* __restrict__ colsum)
{
    int i = blockIdx.x * 256 + threadIdx.x;
    float m = -1e30f, sum = 0.f;
#pragma unroll
    for (int ch = 0; ch < 8; ch++) {
        float mm = pmax[ch * (BB * CC) + i];
        float ss = psum[ch * (BB * CC) + i];
        float nm = fmaxf(m, mm);
        sum = sum * __expf(m - nm) + ss * __expf(mm - nm);
        m = nm;
    }
    colmax[i] = m;
    colsum[i] = sum;
}

// ---------------------------------------------------------------------------
// ksv zero + 4-way N-split partial accumulation via f32 atomics
// ---------------------------------------------------------------------------
__global__ __launch_bounds__(256) void zero_ksv_kernel(float* __restrict__ ksv)
{
    int i = blockIdx.x * 256 + threadIdx.x;   // 256*4096/4 threads, 4 ea
    f32x4 z = {0.f, 0.f, 0.f, 0.f};
    *(f32x4*)&ksv[(size_t)i * 4] = z;
}

__global__ __launch_bounds__(256) void ksv2_kernel(
    const u16* __restrict__ kbf, const u16* __restrict__ vbf,
    const float* __restrict__ colmax, float* __restrict__ ksv)
{
    int bh = blockIdx.x;
    int chunk = blockIdx.y;
    int b = bh >> 3, h = bh & 7;
    int n0 = chunk * 256;
    int n1 = (chunk == 3) ? NN : n0 + 256;

    __shared__ float ke[16][64];
    __shared__ float ve[16][64];
    __shared__ float cm[64];

    int t = threadIdx.x;
    int lrow = t >> 4;
    int lcol = (t & 15) * 4;
    int tx = t & 15, ty = t >> 4;
    if (t < 64) cm[t] = colmax[b * CC + h * HD + t];
    __syncthreads();

    float acc[4][4] = {};
    for (int nb = n0; nb < n1; nb += 16) {
        int n = nb + lrow;
        bool valid = n < n1;
        size_t off = ((size_t)(b * NN + n)) * CC + h * HD + lcol;  // in padded plane
        u16x4 kr = *(const u16x4*)&kbf[off];
        u16x4 vr = *(const u16x4*)&vbf[off];
#pragma unroll
        for (int j = 0; j < 4; j++) {
            ke[lrow][lcol + j] = valid ? __expf(bf2f(kr[j]) - cm[lcol + j]) : 0.f;
            ve[lrow][lcol + j] = valid ? bf2f(vr[j]) : 0.f;
        }
        __syncthreads();
#pragma unroll 4
        for (int d = 0; d < 16; d++) {
            f32x4 ka = *(const f32x4*)&ke[d][ty * 4];
            f32x4 vb = *(const f32x4*)&ve[d][tx * 4];
#pragma unroll
            for (int i = 0; i < 4; i++)
#pragma unroll
                for (int j = 0; j < 4; j++)
                    acc[i][j] = fmaf(ka[i], vb[j], acc[i][j]);
        }
        __syncthreads();
    }

#pragma unroll
    for (int i = 0; i < 4; i++)
#pragma unroll
        for (int j = 0; j < 4; j++)
            atomicAdd(&ksv[(size_t)bh * 4096 + (ty * 4 + i) * 64 + tx * 4 + j], acc[i][j]);
}

// ---------------------------------------------------------------------------
// attbf[b,n,h,:] = bf16(SCALE * q[b,n,h,:] @ (ksv/colsum)[b,h,:,:])
// ---------------------------------------------------------------------------
__global__ __launch_bounds__(256) void factor_att_kernel(
    const u16* __restrict__ qbf, const float* __restrict__ ksv,
    const float* __restrict__ colsum, u16* __restrict__ attbf)
{
    int bh = blockIdx.y;
    int b = bh >> 3, h = bh & 7;
    int n0 = blockIdx.x * 64;
    __shared__ float qs[64][68];
    __shared__ float ks[64][68];

    int t = threadIdx.x;
    int tx = t & 15, ty = t >> 4;

    const float* kbase = ksv + (size_t)bh * 4096;
    const float* csum = colsum + b * CC + h * HD;
#pragma unroll
    for (int i = 0; i < 4; i++) {
        int fidx = t + i * 256;
        int kk = fidx >> 4, vv = (fidx & 15) * 4;
        f32x4 kv = *(const f32x4*)&kbase[(size_t)fidx * 4];
        float inv = 1.f / csum[kk];
#pragma unroll
        for (int j = 0; j < 4; j++) kv[j] *= inv;
        *(f32x4*)&ks[kk][vv] = kv;
    }
#pragma unroll
    for (int i = 0; i < 4; i++) {
        int e = t + i * 256;
        int row = e >> 4, cc0 = (e & 15) * 4;
        u16x4 qv = *(const u16x4*)&qbf[((size_t)(b * NN + n0 + row)) * CC + h * HD + cc0];
#pragma unroll
        for (int j = 0; j < 4; j++) qs[cc0 + j][row] = bf2f(qv[j]);
    }
    __syncthreads();

    float acc[4][4] = {};
#pragma unroll 8
    for (int kk = 0; kk < 64; kk++) {
        f32x4 a4 = *(const f32x4*)&qs[kk][ty * 4];
        f32x4 b4 = *(const f32x4*)&ks[kk][tx * 4];
#pragma unroll
        for (int i = 0; i < 4; i++)
#pragma unroll
            for (int j = 0; j < 4; j++)
                acc[i][j] = fmaf(a4[i], b4[j], acc[i][j]);
    }

#pragma unroll
    for (int i = 0; i < 4; i++) {
        int n = n0 + ty * 4 + i;
        if (n >= NN) continue;
        u16x4 o;
#pragma unroll
        for (int j = 0; j < 4; j++) o[j] = f2bf(SCALE * acc[i][j]);
        *(u16x4*)&attbf[((size_t)(b * NN + n)) * CC + h * HD + tx * 4] = o;
    }
}

// ---------------------------------------------------------------------------
// CRPE: uniform 49-tap conv with expanded weights, 8x8 register blocking
// ---------------------------------------------------------------------------
__global__ __launch_bounds__(256) void conv_ev2_kernel(
    const u16* __restrict__ vbf, const u16* __restrict__ qbf,
    const float* __restrict__ w7, const float* __restrict__ cbx,
    u16* __restrict__ attbf)
{
    int by = blockIdx.x;            // b*32 + y
    int b = by >> 5, y = by & 31;
    int t = threadIdx.x;
    int xo = t >> 6;                // wave-uniform x-octet
    int cg = t & 63;
    int c = cg * 8;
    const int x0 = xo * 8;

    float acc[8][8];
    {
        f32x4 b0 = *(const f32x4*)&cbx[c];
        f32x4 b1 = *(const f32x4*)&cbx[c + 4];
#pragma unroll
        for (int xi = 0; xi < 8; xi++)
#pragma unroll
            for (int j = 0; j < 4; j++) { acc[xi][j] = b0[j]; acc[xi][j + 4] = b1[j]; }
    }

    for (int dy = 0; dy < 7; dy++) {
        int yy = y + dy - 3;
        if (yy < 0 || yy >= 32) continue;
        float wr[7][8];
#pragma unroll
        for (int dx = 0; dx < 7; dx++) {
            *(f32x4*)&wr[dx][0] = *(const f32x4*)&w7[(dy * 7 + dx) * 512 + c];
            *(f32x4*)&wr[dx][4] = *(const f32x4*)&w7[(dy * 7 + dx) * 512 + c + 4];
        }
        const u16* vrow = vbf + ((size_t)(b * NN) + 1 + (size_t)yy * 32) * CC + c;
#pragma unroll
        for (int sxi = 0; sxi < 14; sxi++) {
            int sx = x0 - 3 + sxi;
            if (sx < 0 || sx >= 32) continue;
            u16x8 vv = *(const u16x8*)&vrow[(size_t)sx * CC];
            float vf[8];
#pragma unroll
            for (int j = 0; j < 8; j++) vf[j] = bf2f(vv[j]);
            int lo = sxi - 6 > 0 ? sxi - 6 : 0;
            int hi = sxi < 7 ? sxi : 7;
#pragma unroll
            for (int xi = 0; xi < 8; xi++) {
                if (xi < lo || xi > hi) continue;
                int dx = sxi - xi;
#pragma unroll
                for (int j = 0; j < 8; j++)
                    acc[xi][j] = fmaf(vf[j], wr[dx][j], acc[xi][j]);
            }
        }
    }

#pragma unroll
    for (int xi = 0; xi < 8; xi++) {
        size_t o = ((size_t)(b * NN) + 1 + (size_t)y * 32 + x0 + xi) * CC + c;
        u16x8 qv = *(const u16x8*)&qbf[o];
        u16x8 av = *(const u16x8*)&attbf[o];
        u16x8 ov;
#pragma unroll
        for (int j = 0; j < 8; j++)
            ov[j] = f2bf(bf2f(av[j]) + bf2f(qv[j]) * acc[xi][j]);
        *(u16x8*)&attbf[o] = ov;
    }
}

// ---------------------------------------------------------------------------
extern "C" void kernel_launch(void* const* d_in, const int* in_sizes, int n_in,
                              void* d_out, int out_size, void* d_ws, size_t ws_size,
                              hipStream_t stream)
{
    const float* x     = (const float*)d_in[0];
    const float* Wqkv  = (const float*)d_in[1];
    const float* bqkv  = (const float*)d_in[2];
    const float* Wproj = (const float*)d_in[3];
    const float* bproj = (const float*)d_in[4];
    const float* ck3   = (const float*)d_in[5];
    const float* cb3   = (const float*)d_in[6];
    const float* ck5   = (const float*)d_in[7];
    const float* cb5   = (const float*)d_in[8];
    const float* ck7   = (const float*)d_in[9];
    const float* cb7   = (const float*)d_in[10];
    float* out = (float*)d_out;

    const size_t PLANE = (size_t)MP2 * CC;

    u16* xbf  = (u16*)d_ws;
    u16* qbf  = xbf + PLANE;
    u16* kbf  = qbf + PLANE;
    u16* vbf  = kbf + PLANE;
    u16* wqT  = vbf + PLANE;
    u16* wpT  = wqT + (size_t)1536 * 512;
    float* pmax   = (float*)(wpT + (size_t)512 * 512);
    float* psum   = pmax + 8 * BB * CC;
    float* colmax = psum + 8 * BB * CC;
    float* colsum = colmax + BB * CC;
    float* ksv    = colsum + BB * CC;          // 256*4096 floats
    float* w7     = ksv + (size_t)256 * 4096;  // 49*512
    float* cbx    = w7 + 49 * 512;             // 512
    u16* attbf = xbf;

    // 1) converts + conv-weight expansion + ksv zeroing
    convert_x_kernel<<<(MP2 * CC / 8 + 255) / 256, 256, 0, stream>>>(x, xbf);
    convert_wt_kernel<<<1536 * 64 / 256, 256, 0, stream>>>(Wqkv, wqT, 1536);
    convert_wt_kernel<<<512 * 64 / 256, 256, 0, stream>>>(Wproj, wpT, 512);
    prep_w7_kernel<<<98, 256, 0, stream>>>(ck3, cb3, ck5, cb5, ck7, cb7, w7, cbx);
    zero_ksv_kernel<<<256 * 4096 / 4 / 256, 256, 0, stream>>>(ksv);

    // 2) qkv GEMM (8-phase 256^2) -> bf16 q/k/v planes
    {
        int nwg = 6 * (MP2 / 256);
        gemm8p_kernel<0, 1536, 6><<<nwg, 512, 0, stream>>>(xbf, wqT, bqkv, qbf, nwg);
    }
    // 3) softmax stats
    {
        dim3 grid(CC / 256, BB, 8);
        stats_part_kernel<<<grid, 256, 0, stream>>>(kbf, pmax, psum);
        stats_merge_kernel<<<BB * CC / 256, 256, 0, stream>>>(pmax, psum, colmax, colsum);
    }
    // 4) ksv (4-way N-split, atomic accumulate)
    {
        dim3 grid(BB * HH, 4);
        ksv2_kernel<<<grid, 256, 0, stream>>>(kbf, vbf, colmax, ksv);
    }
    // 5) factor att -> attbf (overlays xbf); /colsum fused here
    {
        dim3 grid((NN + 63) / 64, BB * HH);
        factor_att_kernel<<<grid, 256, 0, stream>>>(qbf, ksv, colsum, attbf);
    }
    // 6) CRPE
    conv_ev2_kernel<<<BB * 32, 256, 0, stream>>>(vbf, qbf, w7, cbx, attbf);
    // 7) proj GEMM (8-phase 256^2) -> out
    {
        int nwg = 2 * (MP2 / 256);
        gemm8p_kernel<1, 512, 2><<<nwg, 512, 0, stream>>>(attbf, wpT, bproj, out, nwg);
    }
}

// Round 5
// 335.002 us; speedup vs baseline: 1.2026x; 1.2026x over previous
//
#include <hip/hip_runtime.h>
#include <hip/hip_bf16.h>

#define BB 32
#define NN 1025
#define CC 512
#define HH 8
#define HD 64
#define MM (BB * NN)        // 32800
#define MP 32896            // 257 * 128 (padded M)
#define KK 512
#define SCALE 0.125f

typedef unsigned short u16;
typedef __attribute__((ext_vector_type(4))) unsigned short u16x4;
typedef __attribute__((ext_vector_type(8))) unsigned short u16x8;
typedef __attribute__((ext_vector_type(4))) float f32x4;
typedef __attribute__((ext_vector_type(8))) __bf16 bf16x8;

__device__ __forceinline__ u16 f2bf(float f) {
    unsigned u = __float_as_uint(f);
    unsigned r = (u + 0x7FFFu + ((u >> 16) & 1u)) >> 16;
    return (u16)r;
}
__device__ __forceinline__ float bf2f(u16 h) {
    return __uint_as_float((unsigned)h << 16);
}

__device__ __forceinline__ void gload16(const u16* g, u16* l) {
    __builtin_amdgcn_global_load_lds(
        (const __attribute__((address_space(1))) unsigned int*)g,
        (__attribute__((address_space(3))) unsigned int*)l, 16, 0, 0);
}

// ---------------------------------------------------------------------------
// convert x (fp32 [MM][512]) -> xbf (bf16 [MP][512]), zero pad rows
// ---------------------------------------------------------------------------
__global__ __launch_bounds__(256) void convert_x_kernel(
    const float* __restrict__ x, u16* __restrict__ xbf)
{
    size_t t = (size_t)blockIdx.x * 256 + threadIdx.x;
    size_t base = t * 8;
    u16x8 o;
    if (base < (size_t)MM * CC) {
        f32x4 a = *(const f32x4*)&x[base];
        f32x4 b = *(const f32x4*)&x[base + 4];
#pragma unroll
        for (int j = 0; j < 4; j++) { o[j] = f2bf(a[j]); o[j + 4] = f2bf(b[j]); }
    } else {
#pragma unroll
        for (int j = 0; j < 8; j++) o[j] = 0;
    }
    *(u16x8*)&xbf[base] = o;
}

// ---------------------------------------------------------------------------
// transpose+convert weights: Wt[n][k] = bf16(W[k][n]);  K = 512
// ---------------------------------------------------------------------------
__global__ __launch_bounds__(256) void convert_wt_kernel(
    const float* __restrict__ W, u16* __restrict__ Wt, int N)
{
    int t = blockIdx.x * 256 + threadIdx.x;
    int n = t >> 6;
    int k0 = (t & 63) * 8;
    u16x8 o;
#pragma unroll
    for (int j = 0; j < 8; j++) o[j] = f2bf(W[(size_t)(k0 + j) * N + n]);
    *(u16x8*)&Wt[(size_t)n * KK + k0] = o;
}

// ---------------------------------------------------------------------------
// expand conv weights into dense [7][7][512] table (+ merged bias [512])
// ---------------------------------------------------------------------------
__global__ __launch_bounds__(256) void prep_w7_kernel(
    const float* __restrict__ ck3, const float* __restrict__ cb3,
    const float* __restrict__ ck5, const float* __restrict__ cb5,
    const float* __restrict__ ck7, const float* __restrict__ cb7,
    float* __restrict__ w7, float* __restrict__ cbx)
{
    int t = blockIdx.x * 256 + threadIdx.x;   // 49*512 = 25088
    if (t >= 49 * 512) return;
    int c = t & 511;
    int tap = t >> 9;
    int dy = tap / 7, dx = tap % 7;
    float w = 0.f;
    if (c < 128) {
        int ry = dy - 2, rx = dx - 2;
        if (ry >= 0 && ry < 3 && rx >= 0 && rx < 3) w = ck3[(ry * 3 + rx) * 128 + c];
    } else if (c < 320) {
        int ry = dy - 1, rx = dx - 1;
        if (ry >= 0 && ry < 5 && rx >= 0 && rx < 5) w = ck5[(ry * 5 + rx) * 192 + (c - 128)];
    } else {
        w = ck7[(dy * 7 + dx) * 192 + (c - 320)];
    }
    w7[tap * 512 + c] = w;
    if (t < 512)
        cbx[t] = (t < 128) ? cb3[t] : (t < 320) ? cb5[t - 128] : cb7[t - 320];
}

// ---------------------------------------------------------------------------
// bf16 MFMA GEMM (2-phase 128x128, BK=32) + XCD-bijective 1D swizzle.
// A [MP][512] bf16, Bt [N][512] bf16. 256 thr, 4 waves 2x2, 4x4 frags.
// MODE 0: scatter bf16 into contiguous q/k/v planes. MODE 1: fp32 out.
// ---------------------------------------------------------------------------
template <int MODE, int NSZ, int GX>
__global__ __launch_bounds__(256) void gemm_bf16_kernel(
    const u16* __restrict__ A, const u16* __restrict__ Bt,
    const float* __restrict__ bias, void* __restrict__ outv, int nwg)
{
    __shared__ __align__(16) u16 lds[2][2][4096];

    // XCD-bijective swizzle: each XCD gets a contiguous chunk of work-ids,
    // so its L2 holds one A row-stripe (~4 MB) + all of B.
    int wg = blockIdx.x;
    {
        int q = nwg >> 3, r = nwg & 7;
        int xcd = wg & 7, pos = wg >> 3;
        wg = (xcd < r ? xcd * (q + 1) : r * (q + 1) + (xcd - r) * q) + pos;
    }
    const int m0 = (wg / GX) * 128;
    const int n0 = (wg % GX) * 128;

    const int t = threadIdx.x;

    const int srow = t >> 2;
    const int ps   = t & 3;
    const int ls   = ps ^ ((srow >> 1) & 3);
    const u16* gA = A  + (size_t)(m0 + srow) * KK + ls * 8;
    const u16* gB = Bt + (size_t)(n0 + srow) * KK + ls * 8;

    const int l  = t & 63;
    const int w  = t >> 6;
    const int wm = (w >> 1) * 64;
    const int wn = (w & 1) * 64;
    const int lr = l & 15;
    const int s  = l >> 4;
    const int ra = wm + lr;
    const int rb = wn + lr;
    const int offA = ra * 32 + (s ^ ((ra >> 1) & 3)) * 8;
    const int offB = rb * 32 + (s ^ ((rb >> 1) & 3)) * 8;

    f32x4 acc[4][4] = {};

#define STAGE(buf, kk_) do {                                        \
        gload16(gA + (kk_),           &lds[buf][0][t * 8]);         \
        gload16(gA + 64 * KK + (kk_), &lds[buf][0][2048 + t * 8]);  \
        gload16(gB + (kk_),           &lds[buf][1][t * 8]);         \
        gload16(gB + 64 * KK + (kk_), &lds[buf][1][2048 + t * 8]);  \
    } while (0)

    STAGE(0, 0);
    __syncthreads();

    int cur = 0;
    for (int step = 0; step < 16; ++step) {
        if (step < 15) STAGE(cur ^ 1, (step + 1) * 32);
        bf16x8 a[4], b[4];
#pragma unroll
        for (int i = 0; i < 4; i++) a[i] = *(const bf16x8*)&lds[cur][0][offA + i * 512];
#pragma unroll
        for (int i = 0; i < 4; i++) b[i] = *(const bf16x8*)&lds[cur][1][offB + i * 512];
#pragma unroll
        for (int i = 0; i < 4; i++)
#pragma unroll
            for (int j = 0; j < 4; j++)
                acc[i][j] = __builtin_amdgcn_mfma_f32_16x16x32_bf16(a[i], b[j], acc[i][j], 0, 0, 0);
        __syncthreads();
        cur ^= 1;
    }
#undef STAGE

    const int row0 = m0 + wm + (l >> 4) * 4;
    const int col0 = n0 + wn + lr;
    float bs[4];
#pragma unroll
    for (int j = 0; j < 4; j++) bs[j] = bias[col0 + j * 16];

    if (MODE == 0) {
        u16* qkv = (u16*)outv;
        const int plane = n0 >> 9;
        u16* pl = qkv + (size_t)plane * ((size_t)MP * CC);
#pragma unroll
        for (int i = 0; i < 4; i++) {
#pragma unroll
            for (int j = 0; j < 4; j++) {
                int gc = (col0 + j * 16) & 511;
#pragma unroll
                for (int r = 0; r < 4; r++) {
                    int gm = row0 + i * 16 + r;
                    pl[(size_t)gm * CC + gc] = f2bf(acc[i][j][r] + bs[j]);
                }
            }
        }
    } else {
        float* out = (float*)outv;
#pragma unroll
        for (int i = 0; i < 4; i++) {
#pragma unroll
            for (int j = 0; j < 4; j++) {
                int gn = col0 + j * 16;
#pragma unroll
                for (int r = 0; r < 4; r++) {
                    int gm = row0 + i * 16 + r;
                    if (gm < MM) out[(size_t)gm * NSZ + gn] = acc[i][j][r] + bs[j];
                }
            }
        }
    }
}

// ---------------------------------------------------------------------------
// softmax stats over N per (b,c): 8 N-chunks, then merge
// ---------------------------------------------------------------------------
__global__ __launch_bounds__(256) void stats_part_kernel(
    const u16* __restrict__ kbf, float* __restrict__ pmax, float* __restrict__ psum)
{
    int c  = blockIdx.x * 256 + threadIdx.x;
    int b  = blockIdx.y;
    int ch = blockIdx.z;
    int n0 = ch * 128, n1 = (ch == 7) ? NN : n0 + 128;
    const u16* col = kbf + (size_t)(b * NN + n0) * CC + c;
    float m = -1e30f, sum = 0.f;
    for (int n = n0; n < n1; n++, col += CC) {
        float val = bf2f(*col);
        float nm = fmaxf(m, val);
        sum = sum * __expf(m - nm) + __expf(val - nm);
        m = nm;
    }
    pmax[(ch * BB + b) * CC + c] = m;
    psum[(ch * BB + b) * CC + c] = sum;
}

__global__ __launch_bounds__(256) void stats_merge_kernel(
    const float* __restrict__ pmax, const float* __restrict__ psum,
    float* __restrict__ colmax, float* __restrict__ colsum)
{
    int i = blockIdx.x * 256 + threadIdx.x;
    float m = -1e30f, sum = 0.f;
#pragma unroll
    for (int ch = 0; ch < 8; ch++) {
        float mm = pmax[ch * (BB * CC) + i];
        float ss = psum[ch * (BB * CC) + i];
        float nm = fmaxf(m, mm);
        sum = sum * __expf(m - nm) + ss * __expf(mm - nm);
        m = nm;
    }
    colmax[i] = m;
    colsum[i] = sum;
}

// ---------------------------------------------------------------------------
// ksv partials: part[chunk][bh][kk][vv] = sum_{n in chunk} exp(k-max) * v
// (no atomics; 4 N-chunks in parallel)
// ---------------------------------------------------------------------------
__global__ __launch_bounds__(256) void ksv_part_kernel(
    const u16* __restrict__ kbf, const u16* __restrict__ vbf,
    const float* __restrict__ colmax, float* __restrict__ part)
{
    int bh = blockIdx.x;
    int chunk = blockIdx.y;
    int b = bh >> 3, h = bh & 7;
    int n0 = chunk * 256;
    int n1 = (chunk == 3) ? NN : n0 + 256;

    __shared__ float ke[16][64];
    __shared__ float ve[16][64];
    __shared__ float cm[64];

    int t = threadIdx.x;
    int lrow = t >> 4;
    int lcol = (t & 15) * 4;
    int tx = t & 15, ty = t >> 4;
    if (t < 64) cm[t] = colmax[b * CC + h * HD + t];
    __syncthreads();

    float acc[4][4] = {};
    for (int nb = n0; nb < n1; nb += 16) {
        int n = nb + lrow;
        bool valid = n < n1;
        size_t off = ((size_t)(b * NN + n)) * CC + h * HD + lcol;  // padded plane
        u16x4 kr = *(const u16x4*)&kbf[off];
        u16x4 vr = *(const u16x4*)&vbf[off];
#pragma unroll
        for (int j = 0; j < 4; j++) {
            ke[lrow][lcol + j] = valid ? __expf(bf2f(kr[j]) - cm[lcol + j]) : 0.f;
            ve[lrow][lcol + j] = valid ? bf2f(vr[j]) : 0.f;
        }
        __syncthreads();
#pragma unroll 4
        for (int d = 0; d < 16; d++) {
            f32x4 ka = *(const f32x4*)&ke[d][ty * 4];
            f32x4 vb = *(const f32x4*)&ve[d][tx * 4];
#pragma unroll
            for (int i = 0; i < 4; i++)
#pragma unroll
                for (int j = 0; j < 4; j++)
                    acc[i][j] = fmaf(ka[i], vb[j], acc[i][j]);
        }
        __syncthreads();
    }

    float* dst = part + ((size_t)chunk * 256 + bh) * 4096;
#pragma unroll
    for (int i = 0; i < 4; i++) {
        f32x4 o = {acc[i][0], acc[i][1], acc[i][2], acc[i][3]};
        *(f32x4*)&dst[(ty * 4 + i) * 64 + tx * 4] = o;
    }
}

// ---------------------------------------------------------------------------
// ksvN = SCALE * (sum_chunk part) / colsum   (normalized+scaled, fp32)
// ---------------------------------------------------------------------------
__global__ __launch_bounds__(256) void ksv_reduce_kernel(
    const float* __restrict__ part, const float* __restrict__ colsum,
    float* __restrict__ ksvN)
{
    int i = blockIdx.x * 256 + threadIdx.x;   // f32x4 units, 256*4096/4 total
    size_t e = (size_t)i * 4;
    int bh = (int)(e >> 12);
    int kk = ((int)e >> 6) & 63;
    int b = bh >> 3, h = bh & 7;
    f32x4 s = *(const f32x4*)&part[e];
#pragma unroll
    for (int c = 1; c < 4; c++) {
        f32x4 p = *(const f32x4*)&part[(size_t)c * 256 * 4096 + e];
#pragma unroll
        for (int j = 0; j < 4; j++) s[j] += p[j];
    }
    float inv = SCALE / colsum[b * CC + h * HD + kk];
#pragma unroll
    for (int j = 0; j < 4; j++) s[j] *= inv;
    *(f32x4*)&ksvN[e] = s;
}

// ---------------------------------------------------------------------------
// FUSED: attbf[b,1+pix,c] = q*(dwconv(v)+cb) + sum_kk q[h,kk]*ksvN[h,kk,vv]
// Block = (b,y); 256 thr = 4 x-octets x 64 channel-octets; 8pix x 8ch each.
// Write-only output (no RMW). n=0 row handled by att0_kernel.
// ---------------------------------------------------------------------------
__global__ __launch_bounds__(256) void fused_attconv_kernel(
    const u16* __restrict__ vbf, const u16* __restrict__ qbf,
    const float* __restrict__ w7, const float* __restrict__ cbx,
    const float* __restrict__ ksvN, u16* __restrict__ attbf)
{
    int by = blockIdx.x;            // b*32 + y
    int b = by >> 5, y = by & 31;
    int t = threadIdx.x;
    int xo = t >> 6;                // wave-uniform x-octet
    int cg = t & 63;
    int c = cg * 8;
    int h = cg >> 3;
    const int x0 = xo * 8;

    float acc[8][8];
    {
        f32x4 b0 = *(const f32x4*)&cbx[c];
        f32x4 b1 = *(const f32x4*)&cbx[c + 4];
#pragma unroll
        for (int xi = 0; xi < 8; xi++)
#pragma unroll
            for (int j = 0; j < 4; j++) { acc[xi][j] = b0[j]; acc[xi][j + 4] = b1[j]; }
    }

    // --- depthwise conv (uniform 49-tap expanded weights) ---
    for (int dy = 0; dy < 7; dy++) {
        int yy = y + dy - 3;
        if (yy < 0 || yy >= 32) continue;           // block-uniform
        float wr[7][8];
#pragma unroll
        for (int dx = 0; dx < 7; dx++) {
            *(f32x4*)&wr[dx][0] = *(const f32x4*)&w7[(dy * 7 + dx) * 512 + c];
            *(f32x4*)&wr[dx][4] = *(const f32x4*)&w7[(dy * 7 + dx) * 512 + c + 4];
        }
        const u16* vrow = vbf + ((size_t)(b * NN) + 1 + (size_t)yy * 32) * CC + c;
#pragma unroll
        for (int sxi = 0; sxi < 14; sxi++) {
            int sx = x0 - 3 + sxi;
            if (sx < 0 || sx >= 32) continue;       // wave-uniform
            u16x8 vv = *(const u16x8*)&vrow[(size_t)sx * CC];
            float vf[8];
#pragma unroll
            for (int j = 0; j < 8; j++) vf[j] = bf2f(vv[j]);
            int lo = sxi - 6 > 0 ? sxi - 6 : 0;
            int hi = sxi < 7 ? sxi : 7;
#pragma unroll
            for (int xi = 0; xi < 8; xi++) {
                if (xi < lo || xi > hi) continue;   // compile-time after unroll
                int dx = sxi - xi;
#pragma unroll
                for (int j = 0; j < 8; j++)
                    acc[xi][j] = fmaf(vf[j], wr[dx][j], acc[xi][j]);
            }
        }
    }

    // --- acc = q ⊙ (conv + bias) ---
    const size_t rowbase = (size_t)(b * NN) + 1 + (size_t)y * 32 + x0;
#pragma unroll
    for (int xi = 0; xi < 8; xi++) {
        u16x8 qv = *(const u16x8*)&qbf[(rowbase + xi) * CC + c];
#pragma unroll
        for (int j = 0; j < 8; j++) acc[xi][j] *= bf2f(qv[j]);
    }

    // --- GEMV: acc += sum_kk q[h,kk] * ksvN[h,kk,vv]  (SCALE/colsum folded) ---
    const float* kbase = ksvN + ((size_t)(b * 8 + h)) * 4096 + (cg & 7) * 8;
    for (int k0 = 0; k0 < 64; k0 += 8) {
        float qk[8][8];
#pragma unroll
        for (int xi = 0; xi < 8; xi++) {
            u16x8 qv = *(const u16x8*)&qbf[(rowbase + xi) * CC + h * 64 + k0];
#pragma unroll
            for (int j = 0; j < 8; j++) qk[xi][j] = bf2f(qv[j]);
        }
#pragma unroll
        for (int kk = 0; kk < 8; kk++) {
            f32x4 k0v = *(const f32x4*)&kbase[(k0 + kk) * 64];
            f32x4 k1v = *(const f32x4*)&kbase[(k0 + kk) * 64 + 4];
#pragma unroll
            for (int xi = 0; xi < 8; xi++) {
#pragma unroll
                for (int j = 0; j < 4; j++) {
                    acc[xi][j]     = fmaf(qk[xi][kk], k0v[j], acc[xi][j]);
                    acc[xi][j + 4] = fmaf(qk[xi][kk], k1v[j], acc[xi][j + 4]);
                }
            }
        }
    }

    // --- store ---
#pragma unroll
    for (int xi = 0; xi < 8; xi++) {
        u16x8 ov;
#pragma unroll
        for (int j = 0; j < 8; j++) ov[j] = f2bf(acc[xi][j]);
        *(u16x8*)&attbf[(rowbase + xi) * CC + c] = ov;
    }
}

// ---------------------------------------------------------------------------
// n=0 row: attbf[b,0,c] = sum_kk q[b,0,h,kk] * ksvN[b,h,kk,c&63]
// ---------------------------------------------------------------------------
__global__ __launch_bounds__(512) void att0_kernel(
    const u16* __restrict__ qbf, const float* __restrict__ ksvN,
    u16* __restrict__ attbf)
{
    int b = blockIdx.x;
    int c = threadIdx.x;           // 0..511
    int h = c >> 6, vv = c & 63;
    const u16* q0 = qbf + (size_t)(b * NN) * CC + h * 64;
    const float* kb = ksvN + ((size_t)(b * 8 + h)) * 4096 + vv;
    float s = 0.f;
#pragma unroll 8
    for (int kk = 0; kk < 64; kk++)
        s = fmaf(bf2f(q0[kk]), kb[kk * 64], s);
    attbf[(size_t)(b * NN) * CC + c] = f2bf(s);
}

// ---------------------------------------------------------------------------
extern "C" void kernel_launch(void* const* d_in, const int* in_sizes, int n_in,
                              void* d_out, int out_size, void* d_ws, size_t ws_size,
                              hipStream_t stream)
{
    const float* x     = (const float*)d_in[0];
    const float* Wqkv  = (const float*)d_in[1];
    const float* bqkv  = (const float*)d_in[2];
    const float* Wproj = (const float*)d_in[3];
    const float* bproj = (const float*)d_in[4];
    const float* ck3   = (const float*)d_in[5];
    const float* cb3   = (const float*)d_in[6];
    const float* ck5   = (const float*)d_in[7];
    const float* cb5   = (const float*)d_in[8];
    const float* ck7   = (const float*)d_in[9];
    const float* cb7   = (const float*)d_in[10];
    float* out = (float*)d_out;

    const size_t PLANE = (size_t)MP * CC;

    u16* xbf  = (u16*)d_ws;
    u16* qbf  = xbf + PLANE;
    u16* kbf  = qbf + PLANE;
    u16* vbf  = kbf + PLANE;
    u16* wqT  = vbf + PLANE;
    u16* wpT  = wqT + (size_t)1536 * 512;
    float* pmax   = (float*)(wpT + (size_t)512 * 512);
    float* psum   = pmax + 8 * BB * CC;
    float* colmax = psum + 8 * BB * CC;
    float* colsum = colmax + BB * CC;
    float* part   = colsum + BB * CC;              // 4 * 256 * 4096
    float* ksvN   = part + (size_t)4 * 256 * 4096; // 256 * 4096
    float* w7     = ksvN + (size_t)256 * 4096;     // 49*512
    float* cbx    = w7 + 49 * 512;                 // 512
    u16* attbf = xbf;                              // alias (x dead after qkv)

    // 1) converts + conv-weight expansion
    convert_x_kernel<<<(int)(PLANE / 8 / 256), 256, 0, stream>>>(x, xbf);
    convert_wt_kernel<<<1536 * 64 / 256, 256, 0, stream>>>(Wqkv, wqT, 1536);
    convert_wt_kernel<<<512 * 64 / 256, 256, 0, stream>>>(Wproj, wpT, 512);
    prep_w7_kernel<<<98, 256, 0, stream>>>(ck3, cb3, ck5, cb5, ck7, cb7, w7, cbx);

    // 2) qkv GEMM -> bf16 q/k/v planes (XCD-swizzled 1D grid)
    {
        int nwg = 12 * (MP / 128);   // 3084
        gemm_bf16_kernel<0, 1536, 12><<<nwg, 256, 0, stream>>>(xbf, wqT, bqkv, qbf, nwg);
    }
    // 3) softmax stats
    {
        dim3 grid(CC / 256, BB, 8);
        stats_part_kernel<<<grid, 256, 0, stream>>>(kbf, pmax, psum);
        stats_merge_kernel<<<BB * CC / 256, 256, 0, stream>>>(pmax, psum, colmax, colsum);
    }
    // 4) ksv partials (4-way N-split) + reduce (folds SCALE/colsum)
    {
        dim3 grid(BB * HH, 4);
        ksv_part_kernel<<<grid, 256, 0, stream>>>(kbf, vbf, colmax, part);
        ksv_reduce_kernel<<<256 * 4096 / 4 / 256, 256, 0, stream>>>(part, colsum, ksvN);
    }
    // 5) fused factor-att + CRPE -> attbf (write-only; overlays xbf)
    fused_attconv_kernel<<<BB * 32, 256, 0, stream>>>(vbf, qbf, w7, cbx, ksvN, attbf);
    att0_kernel<<<BB, 512, 0, stream>>>(qbf, ksvN, attbf);
    // 6) proj GEMM -> out (XCD-swizzled 1D grid)
    {
        int nwg = 4 * (MP / 128);    // 1028
        gemm_bf16_kernel<1, 512, 4><<<nwg, 256, 0, stream>>>(attbf, wpT, bproj, out, nwg);
    }
}

// Round 6
// 323.396 us; speedup vs baseline: 1.2457x; 1.0359x over previous
//
#include <hip/hip_runtime.h>
#include <hip/hip_bf16.h>

#define BB 32
#define NN 1025
#define CC 512
#define HH 8
#define HD 64
#define MM (BB * NN)        // 32800
#define MP 33024            // padded plane rows (fits b*NN + 9*128 tiles)
#define KK 512
#define SCALE 0.125f

typedef unsigned short u16;
typedef __attribute__((ext_vector_type(4))) unsigned short u16x4;
typedef __attribute__((ext_vector_type(8))) unsigned short u16x8;
typedef __attribute__((ext_vector_type(4))) float f32x4;
typedef __attribute__((ext_vector_type(8))) __bf16 bf16x8;

__device__ __forceinline__ u16 f2bf(float f) {
    unsigned u = __float_as_uint(f);
    unsigned r = (u + 0x7FFFu + ((u >> 16) & 1u)) >> 16;
    return (u16)r;
}
__device__ __forceinline__ float bf2f(u16 h) {
    return __uint_as_float((unsigned)h << 16);
}

__device__ __forceinline__ void gload16(const u16* g, u16* l) {
    __builtin_amdgcn_global_load_lds(
        (const __attribute__((address_space(1))) unsigned int*)g,
        (__attribute__((address_space(3))) unsigned int*)l, 16, 0, 0);
}

// ---------------------------------------------------------------------------
// convert x (fp32 [MM][512]) -> xbf (bf16 [MP][512]), zero pad rows
// ---------------------------------------------------------------------------
__global__ __launch_bounds__(256) void convert_x_kernel(
    const float* __restrict__ x, u16* __restrict__ xbf)
{
    size_t t = (size_t)blockIdx.x * 256 + threadIdx.x;
    size_t base = t * 8;
    u16x8 o;
    if (base < (size_t)MM * CC) {
        f32x4 a = *(const f32x4*)&x[base];
        f32x4 b = *(const f32x4*)&x[base + 4];
#pragma unroll
        for (int j = 0; j < 4; j++) { o[j] = f2bf(a[j]); o[j + 4] = f2bf(b[j]); }
    } else {
#pragma unroll
        for (int j = 0; j < 8; j++) o[j] = 0;
    }
    *(u16x8*)&xbf[base] = o;
}

// ---------------------------------------------------------------------------
// transpose+convert weights: Wt[n][k] = bf16(W[k][n]);  K = 512
// ---------------------------------------------------------------------------
__global__ __launch_bounds__(256) void convert_wt_kernel(
    const float* __restrict__ W, u16* __restrict__ Wt, int N)
{
    int t = blockIdx.x * 256 + threadIdx.x;
    int n = t >> 6;
    int k0 = (t & 63) * 8;
    u16x8 o;
#pragma unroll
    for (int j = 0; j < 8; j++) o[j] = f2bf(W[(size_t)(k0 + j) * N + n]);
    *(u16x8*)&Wt[(size_t)n * KK + k0] = o;
}

// ---------------------------------------------------------------------------
// expand conv weights into dense [7][7][512] table (+ merged bias [512])
// ---------------------------------------------------------------------------
__global__ __launch_bounds__(256) void prep_w7_kernel(
    const float* __restrict__ ck3, const float* __restrict__ cb3,
    const float* __restrict__ ck5, const float* __restrict__ cb5,
    const float* __restrict__ ck7, const float* __restrict__ cb7,
    float* __restrict__ w7, float* __restrict__ cbx)
{
    int t = blockIdx.x * 256 + threadIdx.x;   // 49*512 = 25088
    if (t >= 49 * 512) return;
    int c = t & 511;
    int tap = t >> 9;
    int dy = tap / 7, dx = tap % 7;
    float w = 0.f;
    if (c < 128) {
        int ry = dy - 2, rx = dx - 2;
        if (ry >= 0 && ry < 3 && rx >= 0 && rx < 3) w = ck3[(ry * 3 + rx) * 128 + c];
    } else if (c < 320) {
        int ry = dy - 1, rx = dx - 1;
        if (ry >= 0 && ry < 5 && rx >= 0 && rx < 5) w = ck5[(ry * 5 + rx) * 192 + (c - 128)];
    } else {
        w = ck7[(dy * 7 + dx) * 192 + (c - 320)];
    }
    w7[tap * 512 + c] = w;
    if (t < 512)
        cbx[t] = (t < 128) ? cb3[t] : (t < 320) ? cb5[t - 128] : cb7[t - 320];
}

// ---------------------------------------------------------------------------
// bf16 MFMA GEMM (2-phase 128x128, BK=32) + XCD-bijective 1D swizzle.
// MODE 0: scatter bf16 into contiguous q/k/v planes. MODE 1: fp32 out.
// ---------------------------------------------------------------------------
template <int MODE, int NSZ, int GX>
__global__ __launch_bounds__(256) void gemm_bf16_kernel(
    const u16* __restrict__ A, const u16* __restrict__ Bt,
    const float* __restrict__ bias, void* __restrict__ outv, int nwg)
{
    __shared__ __align__(16) u16 lds[2][2][4096];

    int wg = blockIdx.x;
    {
        int q = nwg >> 3, r = nwg & 7;
        int xcd = wg & 7, pos = wg >> 3;
        wg = (xcd < r ? xcd * (q + 1) : r * (q + 1) + (xcd - r) * q) + pos;
    }
    const int m0 = (wg / GX) * 128;
    const int n0 = (wg % GX) * 128;

    const int t = threadIdx.x;

    const int srow = t >> 2;
    const int ps   = t & 3;
    const int ls   = ps ^ ((srow >> 1) & 3);
    const u16* gA = A  + (size_t)(m0 + srow) * KK + ls * 8;
    const u16* gB = Bt + (size_t)(n0 + srow) * KK + ls * 8;

    const int l  = t & 63;
    const int w  = t >> 6;
    const int wm = (w >> 1) * 64;
    const int wn = (w & 1) * 64;
    const int lr = l & 15;
    const int s  = l >> 4;
    const int ra = wm + lr;
    const int rb = wn + lr;
    const int offA = ra * 32 + (s ^ ((ra >> 1) & 3)) * 8;
    const int offB = rb * 32 + (s ^ ((rb >> 1) & 3)) * 8;

    f32x4 acc[4][4] = {};

#define STAGE(buf, kk_) do {                                        \
        gload16(gA + (kk_),           &lds[buf][0][t * 8]);         \
        gload16(gA + 64 * KK + (kk_), &lds[buf][0][2048 + t * 8]);  \
        gload16(gB + (kk_),           &lds[buf][1][t * 8]);         \
        gload16(gB + 64 * KK + (kk_), &lds[buf][1][2048 + t * 8]);  \
    } while (0)

    STAGE(0, 0);
    __syncthreads();

    int cur = 0;
    for (int step = 0; step < 16; ++step) {
        if (step < 15) STAGE(cur ^ 1, (step + 1) * 32);
        bf16x8 a[4], b[4];
#pragma unroll
        for (int i = 0; i < 4; i++) a[i] = *(const bf16x8*)&lds[cur][0][offA + i * 512];
#pragma unroll
        for (int i = 0; i < 4; i++) b[i] = *(const bf16x8*)&lds[cur][1][offB + i * 512];
#pragma unroll
        for (int i = 0; i < 4; i++)
#pragma unroll
            for (int j = 0; j < 4; j++)
                acc[i][j] = __builtin_amdgcn_mfma_f32_16x16x32_bf16(a[i], b[j], acc[i][j], 0, 0, 0);
        __syncthreads();
        cur ^= 1;
    }
#undef STAGE

    const int row0 = m0 + wm + (l >> 4) * 4;
    const int col0 = n0 + wn + lr;
    float bs[4];
#pragma unroll
    for (int j = 0; j < 4; j++) bs[j] = bias[col0 + j * 16];

    if (MODE == 0) {
        u16* qkv = (u16*)outv;
        const int plane = n0 >> 9;
        u16* pl = qkv + (size_t)plane * ((size_t)MP * CC);
#pragma unroll
        for (int i = 0; i < 4; i++) {
#pragma unroll
            for (int j = 0; j < 4; j++) {
                int gc = (col0 + j * 16) & 511;
#pragma unroll
                for (int r = 0; r < 4; r++) {
                    int gm = row0 + i * 16 + r;
                    pl[(size_t)gm * CC + gc] = f2bf(acc[i][j][r] + bs[j]);
                }
            }
        }
    } else {
        float* out = (float*)outv;
#pragma unroll
        for (int i = 0; i < 4; i++) {
#pragma unroll
            for (int j = 0; j < 4; j++) {
                int gn = col0 + j * 16;
#pragma unroll
                for (int r = 0; r < 4; r++) {
                    int gm = row0 + i * 16 + r;
                    if (gm < MM) out[(size_t)gm * NSZ + gn] = acc[i][j][r] + bs[j];
                }
            }
        }
    }
}

// ---------------------------------------------------------------------------
// softmax stats over N per (b,c): 8 N-chunks, then merge
// ---------------------------------------------------------------------------
__global__ __launch_bounds__(256) void stats_part_kernel(
    const u16* __restrict__ kbf, float* __restrict__ pmax, float* __restrict__ psum)
{
    int c  = blockIdx.x * 256 + threadIdx.x;
    int b  = blockIdx.y;
    int ch = blockIdx.z;
    int n0 = ch * 128, n1 = (ch == 7) ? NN : n0 + 128;
    const u16* col = kbf + (size_t)(b * NN + n0) * CC + c;
    float m = -1e30f, sum = 0.f;
    for (int n = n0; n < n1; n++, col += CC) {
        float val = bf2f(*col);
        float nm = fmaxf(m, val);
        sum = sum * __expf(m - nm) + __expf(val - nm);
        m = nm;
    }
    pmax[(ch * BB + b) * CC + c] = m;
    psum[(ch * BB + b) * CC + c] = sum;
}

__global__ __launch_bounds__(256) void stats_merge_kernel(
    const float* __restrict__ pmax, const float* __restrict__ psum,
    float* __restrict__ colmax, float* __restrict__ colsum)
{
    int i = blockIdx.x * 256 + threadIdx.x;
    float m = -1e30f, sum = 0.f;
#pragma unroll
    for (int ch = 0; ch < 8; ch++) {
        float mm = pmax[ch * (BB * CC) + i];
        float ss = psum[ch * (BB * CC) + i];
        float nm = fmaxf(m, mm);
        sum = sum * __expf(m - nm) + ss * __expf(mm - nm);
        m = nm;
    }
    colmax[i] = m;
    colsum[i] = sum;
}

// ---------------------------------------------------------------------------
// ksv partials: part[chunk][bh][kk][vv] = sum_{n in chunk} exp(k-max) * v
// ---------------------------------------------------------------------------
__global__ __launch_bounds__(256) void ksv_part_kernel(
    const u16* __restrict__ kbf, const u16* __restrict__ vbf,
    const float* __restrict__ colmax, float* __restrict__ part)
{
    int bh = blockIdx.x;
    int chunk = blockIdx.y;
    int b = bh >> 3, h = bh & 7;
    int n0 = chunk * 256;
    int n1 = (chunk == 3) ? NN : n0 + 256;

    __shared__ float ke[16][64];
    __shared__ float ve[16][64];
    __shared__ float cm[64];

    int t = threadIdx.x;
    int lrow = t >> 4;
    int lcol = (t & 15) * 4;
    int tx = t & 15, ty = t >> 4;
    if (t < 64) cm[t] = colmax[b * CC + h * HD + t];
    __syncthreads();

    float acc[4][4] = {};
    for (int nb = n0; nb < n1; nb += 16) {
        int n = nb + lrow;
        bool valid = n < n1;
        size_t off = ((size_t)(b * NN + n)) * CC + h * HD + lcol;  // padded plane
        u16x4 kr = *(const u16x4*)&kbf[off];
        u16x4 vr = *(const u16x4*)&vbf[off];
#pragma unroll
        for (int j = 0; j < 4; j++) {
            ke[lrow][lcol + j] = valid ? __expf(bf2f(kr[j]) - cm[lcol + j]) : 0.f;
            ve[lrow][lcol + j] = valid ? bf2f(vr[j]) : 0.f;
        }
        __syncthreads();
#pragma unroll 4
        for (int d = 0; d < 16; d++) {
            f32x4 ka = *(const f32x4*)&ke[d][ty * 4];
            f32x4 vb = *(const f32x4*)&ve[d][tx * 4];
#pragma unroll
            for (int i = 0; i < 4; i++)
#pragma unroll
                for (int j = 0; j < 4; j++)
                    acc[i][j] = fmaf(ka[i], vb[j], acc[i][j]);
        }
        __syncthreads();
    }

    float* dst = part + ((size_t)chunk * 256 + bh) * 4096;
#pragma unroll
    for (int i = 0; i < 4; i++) {
        f32x4 o = {acc[i][0], acc[i][1], acc[i][2], acc[i][3]};
        *(f32x4*)&dst[(ty * 4 + i) * 64 + tx * 4] = o;
    }
}

// ---------------------------------------------------------------------------
// ksvT[bh][vv][kk] = bf16( SCALE * (sum_chunk part[bh][kk][vv]) / colsum[kk] )
// (transposed + normalized: ready as MFMA B-operand)
// ---------------------------------------------------------------------------
__global__ __launch_bounds__(256) void ksv_reduceT_kernel(
    const float* __restrict__ part, const float* __restrict__ colsum,
    u16* __restrict__ ksvT)
{
    int i = blockIdx.x * 256 + threadIdx.x;   // f32x4 units
    size_t e = (size_t)i * 4;
    int bh = (int)(e >> 12);
    int kk = ((int)e >> 6) & 63;
    int vv0 = (int)e & 63;
    int b = bh >> 3, h = bh & 7;
    f32x4 s = *(const f32x4*)&part[e];
#pragma unroll
    for (int c = 1; c < 4; c++) {
        f32x4 p = *(const f32x4*)&part[(size_t)c * 256 * 4096 + e];
#pragma unroll
        for (int j = 0; j < 4; j++) s[j] += p[j];
    }
    float inv = SCALE / colsum[b * CC + h * HD + kk];
#pragma unroll
    for (int j = 0; j < 4; j++)
        ksvT[(size_t)bh * 4096 + (vv0 + j) * 64 + kk] = f2bf(s[j] * inv);
}

// ---------------------------------------------------------------------------
// factor att via MFMA: attbf[b,n,h,:] = bf16( q[b,n,h,:] @ ksvT[b,h]^T )
// Block: 128 rows x 64 cols for one (b,h); 4 waves of 32 rows. All n incl 0.
// ---------------------------------------------------------------------------
__global__ __launch_bounds__(256) void factor_mfma_kernel(
    const u16* __restrict__ qbf, const u16* __restrict__ ksvT,
    u16* __restrict__ attbf)
{
    int bh = blockIdx.y;
    int b = bh >> 3, h = bh & 7;
    int n0 = blockIdx.x * 128;

    __shared__ __align__(16) u16 lq[128 * 64];
    __shared__ __align__(16) u16 lk[64 * 64];

    int t = threadIdx.x;
    // stage q tile (rows stay inside padded plane)
#pragma unroll
    for (int i = 0; i < 4; i++) {
        int idx = t + i * 256;
        int row = idx >> 3, sl = idx & 7;
        u16x8 v = *(const u16x8*)&qbf[((size_t)(b * NN + n0 + row)) * CC + h * HD + sl * 8];
        *(u16x8*)&lq[row * 64 + ((sl ^ (row & 7)) * 8)] = v;
    }
    // stage ksvT
#pragma unroll
    for (int i = 0; i < 2; i++) {
        int idx = t + i * 256;
        int col = idx >> 3, sl = idx & 7;
        u16x8 v = *(const u16x8*)&ksvT[(size_t)bh * 4096 + col * 64 + sl * 8];
        *(u16x8*)&lk[col * 64 + ((sl ^ (col & 7)) * 8)] = v;
    }
    __syncthreads();

    int l = t & 63, w = t >> 6;
    int lr = l & 15, ls = l >> 4;
    f32x4 acc[2][4] = {};
#pragma unroll
    for (int kf = 0; kf < 2; kf++) {
        bf16x8 a[2], bf[4];
#pragma unroll
        for (int i = 0; i < 2; i++) {
            int row = w * 32 + i * 16 + lr;
            int sl = kf * 4 + ls;
            a[i] = *(const bf16x8*)&lq[row * 64 + ((sl ^ (row & 7)) * 8)];
        }
#pragma unroll
        for (int j = 0; j < 4; j++) {
            int col = j * 16 + lr;
            int sl = kf * 4 + ls;
            bf[j] = *(const bf16x8*)&lk[col * 64 + ((sl ^ (col & 7)) * 8)];
        }
#pragma unroll
        for (int i = 0; i < 2; i++)
#pragma unroll
            for (int j = 0; j < 4; j++)
                acc[i][j] = __builtin_amdgcn_mfma_f32_16x16x32_bf16(a[i], bf[j], acc[i][j], 0, 0, 0);
    }

#pragma unroll
    for (int i = 0; i < 2; i++) {
#pragma unroll
        for (int r = 0; r < 4; r++) {
            int n = n0 + w * 32 + i * 16 + ls * 4 + r;
            if (n >= NN) continue;
            u16* dst = attbf + ((size_t)(b * NN + n)) * CC + h * HD;
#pragma unroll
            for (int j = 0; j < 4; j++)
                dst[j * 16 + lr] = f2bf(acc[i][j][r]);
        }
    }
}

// ---------------------------------------------------------------------------
// CRPE RMW: attbf[b,1+pix,c..c+4] += q * (dwconv(v)+cb); 8 px x 4 ch / thread
// Block = (b, y, chalf): 256 thr = 4 x-octets x 64 channel-quads.
// ---------------------------------------------------------------------------
__global__ __launch_bounds__(256) void conv_rmw_kernel(
    const u16* __restrict__ vbf, const u16* __restrict__ qbf,
    const float* __restrict__ w7, const float* __restrict__ cbx,
    u16* __restrict__ attbf)
{
    int blk = blockIdx.x;           // (b*32 + y)*2 + chalf
    int chalf = blk & 1;
    int by = blk >> 1;
    int b = by >> 5, y = by & 31;
    int t = threadIdx.x;
    int xo = t >> 6;                // wave-uniform x-octet
    int c = (chalf * 64 + (t & 63)) * 4;
    const int x0 = xo * 8;

    float acc[8][4];
    {
        f32x4 b0 = *(const f32x4*)&cbx[c];
#pragma unroll
        for (int xi = 0; xi < 8; xi++)
#pragma unroll
            for (int j = 0; j < 4; j++) acc[xi][j] = b0[j];
    }

    for (int dy = 0; dy < 7; dy++) {
        int yy = y + dy - 3;
        if (yy < 0 || yy >= 32) continue;           // block-uniform
        float wr[7][4];
#pragma unroll
        for (int dx = 0; dx < 7; dx++)
            *(f32x4*)&wr[dx][0] = *(const f32x4*)&w7[(dy * 7 + dx) * 512 + c];
        const u16* vrow = vbf + ((size_t)(b * NN) + 1 + (size_t)yy * 32) * CC + c;
#pragma unroll
        for (int sxi = 0; sxi < 14; sxi++) {
            int sx = x0 - 3 + sxi;
            if (sx < 0 || sx >= 32) continue;       // wave-uniform
            u16x4 vv = *(const u16x4*)&vrow[(size_t)sx * CC];
            float vf[4];
#pragma unroll
            for (int j = 0; j < 4; j++) vf[j] = bf2f(vv[j]);
            int lo = sxi - 6 > 0 ? sxi - 6 : 0;
            int hi = sxi < 7 ? sxi : 7;
#pragma unroll
            for (int xi = 0; xi < 8; xi++) {
                if (xi < lo || xi > hi) continue;   // compile-time after unroll
                int dx = sxi - xi;
#pragma unroll
                for (int j = 0; j < 4; j++)
                    acc[xi][j] = fmaf(vf[j], wr[dx][j], acc[xi][j]);
            }
        }
    }

    const size_t rowbase = (size_t)(b * NN) + 1 + (size_t)y * 32 + x0;
#pragma unroll
    for (int xi = 0; xi < 8; xi++) {
        size_t o = (rowbase + xi) * CC + c;
        u16x4 qv = *(const u16x4*)&qbf[o];
        u16x4 av = *(const u16x4*)&attbf[o];
        u16x4 ov;
#pragma unroll
        for (int j = 0; j < 4; j++)
            ov[j] = f2bf(bf2f(av[j]) + bf2f(qv[j]) * acc[xi][j]);
        *(u16x4*)&attbf[o] = ov;
    }
}

// ---------------------------------------------------------------------------
extern "C" void kernel_launch(void* const* d_in, const int* in_sizes, int n_in,
                              void* d_out, int out_size, void* d_ws, size_t ws_size,
                              hipStream_t stream)
{
    const float* x     = (const float*)d_in[0];
    const float* Wqkv  = (const float*)d_in[1];
    const float* bqkv  = (const float*)d_in[2];
    const float* Wproj = (const float*)d_in[3];
    const float* bproj = (const float*)d_in[4];
    const float* ck3   = (const float*)d_in[5];
    const float* cb3   = (const float*)d_in[6];
    const float* ck5   = (const float*)d_in[7];
    const float* cb5   = (const float*)d_in[8];
    const float* ck7   = (const float*)d_in[9];
    const float* cb7   = (const float*)d_in[10];
    float* out = (float*)d_out;

    const size_t PLANE = (size_t)MP * CC;

    u16* xbf  = (u16*)d_ws;
    u16* qbf  = xbf + PLANE;
    u16* kbf  = qbf + PLANE;
    u16* vbf  = kbf + PLANE;
    u16* wqT  = vbf + PLANE;
    u16* wpT  = wqT + (size_t)1536 * 512;
    u16* ksvT = wpT + (size_t)512 * 512;           // 256*4096 bf16
    float* pmax   = (float*)(ksvT + (size_t)256 * 4096);
    float* psum   = pmax + 8 * BB * CC;
    float* colmax = psum + 8 * BB * CC;
    float* colsum = colmax + BB * CC;
    float* part   = colsum + BB * CC;              // 4 * 256 * 4096 f32
    float* w7     = part + (size_t)4 * 256 * 4096; // 49*512
    float* cbx    = w7 + 49 * 512;                 // 512
    u16* attbf = xbf;                              // alias (x dead after qkv)

    // 1) converts + conv-weight expansion
    convert_x_kernel<<<(int)(PLANE / 8 / 256), 256, 0, stream>>>(x, xbf);
    convert_wt_kernel<<<1536 * 64 / 256, 256, 0, stream>>>(Wqkv, wqT, 1536);
    convert_wt_kernel<<<512 * 64 / 256, 256, 0, stream>>>(Wproj, wpT, 512);
    prep_w7_kernel<<<98, 256, 0, stream>>>(ck3, cb3, ck5, cb5, ck7, cb7, w7, cbx);

    // 2) qkv GEMM -> bf16 q/k/v planes
    {
        int nwg = 12 * (MP / 128);   // 3096
        gemm_bf16_kernel<0, 1536, 12><<<nwg, 256, 0, stream>>>(xbf, wqT, bqkv, qbf, nwg);
    }
    // 3) softmax stats
    {
        dim3 grid(CC / 256, BB, 8);
        stats_part_kernel<<<grid, 256, 0, stream>>>(kbf, pmax, psum);
        stats_merge_kernel<<<BB * CC / 256, 256, 0, stream>>>(pmax, psum, colmax, colsum);
    }
    // 4) ksv partials + transpose-reduce (folds SCALE/colsum, emits bf16 B^T)
    {
        dim3 grid(BB * HH, 4);
        ksv_part_kernel<<<grid, 256, 0, stream>>>(kbf, vbf, colmax, part);
        ksv_reduceT_kernel<<<256 * 4096 / 4 / 256, 256, 0, stream>>>(part, colsum, ksvT);
    }
    // 5) factor att via MFMA -> attbf (all n, incl n=0)
    {
        dim3 grid((NN + 127) / 128, BB * HH);      // 9 x 256
        factor_mfma_kernel<<<grid, 256, 0, stream>>>(qbf, ksvT, attbf);
    }
    // 6) CRPE RMW
    conv_rmw_kernel<<<BB * 32 * 2, 256, 0, stream>>>(vbf, qbf, w7, cbx, attbf);
    // 7) proj GEMM -> out
    {
        int nwg = 4 * (MP / 128);    // 1032
        gemm_bf16_kernel<1, 512, 4><<<nwg, 256, 0, stream>>>(attbf, wpT, bproj, out, nwg);
    }
}

// Round 7
// 293.384 us; speedup vs baseline: 1.3731x; 1.1023x over previous
//
#include <hip/hip_runtime.h>
#include <hip/hip_bf16.h>

#define BB 32
#define NN 1025
#define CC 512
#define HH 8
#define HD 64
#define MM (BB * NN)        // 32800
#define MP 33024            // padded plane rows (fits b*NN + 9*128 tiles)
#define KK 512
#define SCALE 0.125f

typedef unsigned short u16;
typedef __attribute__((ext_vector_type(4))) unsigned short u16x4;
typedef __attribute__((ext_vector_type(8))) unsigned short u16x8;
typedef __attribute__((ext_vector_type(4))) float f32x4;
typedef __attribute__((ext_vector_type(8))) __bf16 bf16x8;

__device__ __forceinline__ u16 f2bf(float f) {
    unsigned u = __float_as_uint(f);
    unsigned r = (u + 0x7FFFu + ((u >> 16) & 1u)) >> 16;
    return (u16)r;
}
__device__ __forceinline__ float bf2f(u16 h) {
    return __uint_as_float((unsigned)h << 16);
}

__device__ __forceinline__ void gload16(const u16* g, u16* l) {
    __builtin_amdgcn_global_load_lds(
        (const __attribute__((address_space(1))) unsigned int*)g,
        (__attribute__((address_space(3))) unsigned int*)l, 16, 0, 0);
}

// ---------------------------------------------------------------------------
// convert x (fp32 [MM][512]) -> xbf (bf16 [MP][512]), zero pad rows
// ---------------------------------------------------------------------------
__global__ __launch_bounds__(256) void convert_x_kernel(
    const float* __restrict__ x, u16* __restrict__ xbf)
{
    size_t t = (size_t)blockIdx.x * 256 + threadIdx.x;
    size_t base = t * 8;
    u16x8 o;
    if (base < (size_t)MM * CC) {
        f32x4 a = *(const f32x4*)&x[base];
        f32x4 b = *(const f32x4*)&x[base + 4];
#pragma unroll
        for (int j = 0; j < 4; j++) { o[j] = f2bf(a[j]); o[j + 4] = f2bf(b[j]); }
    } else {
#pragma unroll
        for (int j = 0; j < 8; j++) o[j] = 0;
    }
    *(u16x8*)&xbf[base] = o;
}

// ---------------------------------------------------------------------------
// transpose+convert weights: Wt[n][k] = bf16(W[k][n]);  K = 512
// ---------------------------------------------------------------------------
__global__ __launch_bounds__(256) void convert_wt_kernel(
    const float* __restrict__ W, u16* __restrict__ Wt, int N)
{
    int t = blockIdx.x * 256 + threadIdx.x;
    int n = t >> 6;
    int k0 = (t & 63) * 8;
    u16x8 o;
#pragma unroll
    for (int j = 0; j < 8; j++) o[j] = f2bf(W[(size_t)(k0 + j) * N + n]);
    *(u16x8*)&Wt[(size_t)n * KK + k0] = o;
}

// ---------------------------------------------------------------------------
// expand conv weights into dense [7][7][512] table (+ merged bias [512])
// ---------------------------------------------------------------------------
__global__ __launch_bounds__(256) void prep_w7_kernel(
    const float* __restrict__ ck3, const float* __restrict__ cb3,
    const float* __restrict__ ck5, const float* __restrict__ cb5,
    const float* __restrict__ ck7, const float* __restrict__ cb7,
    float* __restrict__ w7, float* __restrict__ cbx)
{
    int t = blockIdx.x * 256 + threadIdx.x;   // 49*512 = 25088
    if (t >= 49 * 512) return;
    int c = t & 511;
    int tap = t >> 9;
    int dy = tap / 7, dx = tap % 7;
    float w = 0.f;
    if (c < 128) {
        int ry = dy - 2, rx = dx - 2;
        if (ry >= 0 && ry < 3 && rx >= 0 && rx < 3) w = ck3[(ry * 3 + rx) * 128 + c];
    } else if (c < 320) {
        int ry = dy - 1, rx = dx - 1;
        if (ry >= 0 && ry < 5 && rx >= 0 && rx < 5) w = ck5[(ry * 5 + rx) * 192 + (c - 128)];
    } else {
        w = ck7[(dy * 7 + dx) * 192 + (c - 320)];
    }
    w7[tap * 512 + c] = w;
    if (t < 512)
        cbx[t] = (t < 128) ? cb3[t] : (t < 320) ? cb5[t - 128] : cb7[t - 320];
}

// ---------------------------------------------------------------------------
// bf16 MFMA GEMM (2-phase 128x128, BK=32) + XCD-bijective 1D swizzle.
// MODE 0: scatter bf16 into contiguous q/k/v planes. MODE 1: fp32 out.
// ---------------------------------------------------------------------------
template <int MODE, int NSZ, int GX>
__global__ __launch_bounds__(256) void gemm_bf16_kernel(
    const u16* __restrict__ A, const u16* __restrict__ Bt,
    const float* __restrict__ bias, void* __restrict__ outv, int nwg)
{
    __shared__ __align__(16) u16 lds[2][2][4096];

    int wg = blockIdx.x;
    {
        int q = nwg >> 3, r = nwg & 7;
        int xcd = wg & 7, pos = wg >> 3;
        wg = (xcd < r ? xcd * (q + 1) : r * (q + 1) + (xcd - r) * q) + pos;
    }
    const int m0 = (wg / GX) * 128;
    const int n0 = (wg % GX) * 128;

    const int t = threadIdx.x;

    const int srow = t >> 2;
    const int ps   = t & 3;
    const int ls   = ps ^ ((srow >> 1) & 3);
    const u16* gA = A  + (size_t)(m0 + srow) * KK + ls * 8;
    const u16* gB = Bt + (size_t)(n0 + srow) * KK + ls * 8;

    const int l  = t & 63;
    const int w  = t >> 6;
    const int wm = (w >> 1) * 64;
    const int wn = (w & 1) * 64;
    const int lr = l & 15;
    const int s  = l >> 4;
    const int ra = wm + lr;
    const int rb = wn + lr;
    const int offA = ra * 32 + (s ^ ((ra >> 1) & 3)) * 8;
    const int offB = rb * 32 + (s ^ ((rb >> 1) & 3)) * 8;

    f32x4 acc[4][4] = {};

#define STAGE(buf, kk_) do {                                        \
        gload16(gA + (kk_),           &lds[buf][0][t * 8]);         \
        gload16(gA + 64 * KK + (kk_), &lds[buf][0][2048 + t * 8]);  \
        gload16(gB + (kk_),           &lds[buf][1][t * 8]);         \
        gload16(gB + 64 * KK + (kk_), &lds[buf][1][2048 + t * 8]);  \
    } while (0)

    STAGE(0, 0);
    __syncthreads();

    int cur = 0;
    for (int step = 0; step < 16; ++step) {
        if (step < 15) STAGE(cur ^ 1, (step + 1) * 32);
        bf16x8 a[4], b[4];
#pragma unroll
        for (int i = 0; i < 4; i++) a[i] = *(const bf16x8*)&lds[cur][0][offA + i * 512];
#pragma unroll
        for (int i = 0; i < 4; i++) b[i] = *(const bf16x8*)&lds[cur][1][offB + i * 512];
#pragma unroll
        for (int i = 0; i < 4; i++)
#pragma unroll
            for (int j = 0; j < 4; j++)
                acc[i][j] = __builtin_amdgcn_mfma_f32_16x16x32_bf16(a[i], b[j], acc[i][j], 0, 0, 0);
        __syncthreads();
        cur ^= 1;
    }
#undef STAGE

    const int row0 = m0 + wm + (l >> 4) * 4;
    const int col0 = n0 + wn + lr;
    float bs[4];
#pragma unroll
    for (int j = 0; j < 4; j++) bs[j] = bias[col0 + j * 16];

    if (MODE == 0) {
        u16* qkv = (u16*)outv;
        const int plane = n0 >> 9;
        u16* pl = qkv + (size_t)plane * ((size_t)MP * CC);
#pragma unroll
        for (int i = 0; i < 4; i++) {
#pragma unroll
            for (int j = 0; j < 4; j++) {
                int gc = (col0 + j * 16) & 511;
#pragma unroll
                for (int r = 0; r < 4; r++) {
                    int gm = row0 + i * 16 + r;
                    pl[(size_t)gm * CC + gc] = f2bf(acc[i][j][r] + bs[j]);
                }
            }
        }
    } else {
        float* out = (float*)outv;
#pragma unroll
        for (int i = 0; i < 4; i++) {
#pragma unroll
            for (int j = 0; j < 4; j++) {
                int gn = col0 + j * 16;
#pragma unroll
                for (int r = 0; r < 4; r++) {
                    int gm = row0 + i * 16 + r;
                    if (gm < MM) out[(size_t)gm * NSZ + gn] = acc[i][j][r] + bs[j];
                }
            }
        }
    }
}

// ---------------------------------------------------------------------------
// softmax stats over N per (b,c): 8 N-chunks, then merge
// ---------------------------------------------------------------------------
__global__ __launch_bounds__(256) void stats_part_kernel(
    const u16* __restrict__ kbf, float* __restrict__ pmax, float* __restrict__ psum)
{
    int c  = blockIdx.x * 256 + threadIdx.x;
    int b  = blockIdx.y;
    int ch = blockIdx.z;
    int n0 = ch * 128, n1 = (ch == 7) ? NN : n0 + 128;
    const u16* col = kbf + (size_t)(b * NN + n0) * CC + c;
    float m = -1e30f, sum = 0.f;
    for (int n = n0; n < n1; n++, col += CC) {
        float val = bf2f(*col);
        float nm = fmaxf(m, val);
        sum = sum * __expf(m - nm) + __expf(val - nm);
        m = nm;
    }
    pmax[(ch * BB + b) * CC + c] = m;
    psum[(ch * BB + b) * CC + c] = sum;
}

__global__ __launch_bounds__(256) void stats_merge_kernel(
    const float* __restrict__ pmax, const float* __restrict__ psum,
    float* __restrict__ colmax, float* __restrict__ colsum)
{
    int i = blockIdx.x * 256 + threadIdx.x;
    float m = -1e30f, sum = 0.f;
#pragma unroll
    for (int ch = 0; ch < 8; ch++) {
        float mm = pmax[ch * (BB * CC) + i];
        float ss = psum[ch * (BB * CC) + i];
        float nm = fmaxf(m, mm);
        sum = sum * __expf(m - nm) + ss * __expf(mm - nm);
        m = nm;
    }
    colmax[i] = m;
    colsum[i] = sum;
}

// ---------------------------------------------------------------------------
// ksv partials: part[chunk][bh][kk][vv] = sum_{n in chunk} exp(k-max) * v
// ---------------------------------------------------------------------------
__global__ __launch_bounds__(256) void ksv_part_kernel(
    const u16* __restrict__ kbf, const u16* __restrict__ vbf,
    const float* __restrict__ colmax, float* __restrict__ part)
{
    int bh = blockIdx.x;
    int chunk = blockIdx.y;
    int b = bh >> 3, h = bh & 7;
    int n0 = chunk * 256;
    int n1 = (chunk == 3) ? NN : n0 + 256;

    __shared__ float ke[16][64];
    __shared__ float ve[16][64];
    __shared__ float cm[64];

    int t = threadIdx.x;
    int lrow = t >> 4;
    int lcol = (t & 15) * 4;
    int tx = t & 15, ty = t >> 4;
    if (t < 64) cm[t] = colmax[b * CC + h * HD + t];
    __syncthreads();

    float acc[4][4] = {};
    for (int nb = n0; nb < n1; nb += 16) {
        int n = nb + lrow;
        bool valid = n < n1;
        size_t off = ((size_t)(b * NN + n)) * CC + h * HD + lcol;  // padded plane
        u16x4 kr = *(const u16x4*)&kbf[off];
        u16x4 vr = *(const u16x4*)&vbf[off];
#pragma unroll
        for (int j = 0; j < 4; j++) {
            ke[lrow][lcol + j] = valid ? __expf(bf2f(kr[j]) - cm[lcol + j]) : 0.f;
            ve[lrow][lcol + j] = valid ? bf2f(vr[j]) : 0.f;
        }
        __syncthreads();
#pragma unroll 4
        for (int d = 0; d < 16; d++) {
            f32x4 ka = *(const f32x4*)&ke[d][ty * 4];
            f32x4 vb = *(const f32x4*)&ve[d][tx * 4];
#pragma unroll
            for (int i = 0; i < 4; i++)
#pragma unroll
                for (int j = 0; j < 4; j++)
                    acc[i][j] = fmaf(ka[i], vb[j], acc[i][j]);
        }
        __syncthreads();
    }

    float* dst = part + ((size_t)chunk * 256 + bh) * 4096;
#pragma unroll
    for (int i = 0; i < 4; i++) {
        f32x4 o = {acc[i][0], acc[i][1], acc[i][2], acc[i][3]};
        *(f32x4*)&dst[(ty * 4 + i) * 64 + tx * 4] = o;
    }
}

// ---------------------------------------------------------------------------
// ksvT[bh][vv][kk] = bf16( SCALE * (sum_chunk part[bh][kk][vv]) / colsum[kk] )
// ---------------------------------------------------------------------------
__global__ __launch_bounds__(256) void ksv_reduceT_kernel(
    const float* __restrict__ part, const float* __restrict__ colsum,
    u16* __restrict__ ksvT)
{
    int i = blockIdx.x * 256 + threadIdx.x;   // f32x4 units
    size_t e = (size_t)i * 4;
    int bh = (int)(e >> 12);
    int kk = ((int)e >> 6) & 63;
    int vv0 = (int)e & 63;
    int b = bh >> 3, h = bh & 7;
    f32x4 s = *(const f32x4*)&part[e];
#pragma unroll
    for (int c = 1; c < 4; c++) {
        f32x4 p = *(const f32x4*)&part[(size_t)c * 256 * 4096 + e];
#pragma unroll
        for (int j = 0; j < 4; j++) s[j] += p[j];
    }
    float inv = SCALE / colsum[b * CC + h * HD + kk];
#pragma unroll
    for (int j = 0; j < 4; j++)
        ksvT[(size_t)bh * 4096 + (vv0 + j) * 64 + kk] = f2bf(s[j] * inv);
}

// ---------------------------------------------------------------------------
// factor att via MFMA: attbf[b,n,h,:] = bf16( q[b,n,h,:] @ ksvT[b,h]^T )
// ---------------------------------------------------------------------------
__global__ __launch_bounds__(256) void factor_mfma_kernel(
    const u16* __restrict__ qbf, const u16* __restrict__ ksvT,
    u16* __restrict__ attbf)
{
    int bh = blockIdx.y;
    int b = bh >> 3, h = bh & 7;
    int n0 = blockIdx.x * 128;

    __shared__ __align__(16) u16 lq[128 * 64];
    __shared__ __align__(16) u16 lk[64 * 64];

    int t = threadIdx.x;
#pragma unroll
    for (int i = 0; i < 4; i++) {
        int idx = t + i * 256;
        int row = idx >> 3, sl = idx & 7;
        u16x8 v = *(const u16x8*)&qbf[((size_t)(b * NN + n0 + row)) * CC + h * HD + sl * 8];
        *(u16x8*)&lq[row * 64 + ((sl ^ (row & 7)) * 8)] = v;
    }
#pragma unroll
    for (int i = 0; i < 2; i++) {
        int idx = t + i * 256;
        int col = idx >> 3, sl = idx & 7;
        u16x8 v = *(const u16x8*)&ksvT[(size_t)bh * 4096 + col * 64 + sl * 8];
        *(u16x8*)&lk[col * 64 + ((sl ^ (col & 7)) * 8)] = v;
    }
    __syncthreads();

    int l = t & 63, w = t >> 6;
    int lr = l & 15, ls = l >> 4;
    f32x4 acc[2][4] = {};
#pragma unroll
    for (int kf = 0; kf < 2; kf++) {
        bf16x8 a[2], bf[4];
#pragma unroll
        for (int i = 0; i < 2; i++) {
            int row = w * 32 + i * 16 + lr;
            int sl = kf * 4 + ls;
            a[i] = *(const bf16x8*)&lq[row * 64 + ((sl ^ (row & 7)) * 8)];
        }
#pragma unroll
        for (int j = 0; j < 4; j++) {
            int col = j * 16 + lr;
            int sl = kf * 4 + ls;
            bf[j] = *(const bf16x8*)&lk[col * 64 + ((sl ^ (col & 7)) * 8)];
        }
#pragma unroll
        for (int i = 0; i < 2; i++)
#pragma unroll
            for (int j = 0; j < 4; j++)
                acc[i][j] = __builtin_amdgcn_mfma_f32_16x16x32_bf16(a[i], bf[j], acc[i][j], 0, 0, 0);
    }

#pragma unroll
    for (int i = 0; i < 2; i++) {
#pragma unroll
        for (int r = 0; r < 4; r++) {
            int n = n0 + w * 32 + i * 16 + ls * 4 + r;
            if (n >= NN) continue;
            u16* dst = attbf + ((size_t)(b * NN + n)) * CC + h * HD;
#pragma unroll
            for (int j = 0; j < 4; j++)
                dst[j * 16 + lr] = f2bf(acc[i][j][r]);
        }
    }
}

// ---------------------------------------------------------------------------
// CRPE RMW v3: branchless clamped tap loads, batched per dy-row.
// attbf[b,1+pix,c..c+4] += q * (dwconv(v)+cb); 8 px x 4 ch / thread.
// Block = (b, y, chalf): 256 thr = 4 x-octets x 64 channel-quads.
// ---------------------------------------------------------------------------
__global__ __launch_bounds__(256) void conv_rmw_kernel(
    const u16* __restrict__ vbf, const u16* __restrict__ qbf,
    const float* __restrict__ w7, const float* __restrict__ cbx,
    u16* __restrict__ attbf)
{
    int blk = blockIdx.x;           // (b*32 + y)*2 + chalf
    int chalf = blk & 1;
    int by = blk >> 1;
    int b = by >> 5, y = by & 31;
    int t = threadIdx.x;
    int xo = t >> 6;                // wave-uniform x-octet
    int c = (chalf * 64 + (t & 63)) * 4;
    const int x0 = xo * 8;

    // per-sxi validity (wave-uniform, compile-time-ish after unroll) + clamp
    const u16* vimg = vbf + ((size_t)(b * NN) + 1) * CC + c;

    float acc[8][4];
    {
        f32x4 b0 = *(const f32x4*)&cbx[c];
#pragma unroll
        for (int xi = 0; xi < 8; xi++)
#pragma unroll
            for (int j = 0; j < 4; j++) acc[xi][j] = b0[j];
    }

    for (int dy = 0; dy < 7; dy++) {
        int yy = y + dy - 3;
        if (yy < 0 || yy >= 32) continue;            // block-uniform skip
        // weights for this dy row
        float wr[7][4];
#pragma unroll
        for (int dx = 0; dx < 7; dx++)
            *(f32x4*)&wr[dx][0] = *(const f32x4*)&w7[(dy * 7 + dx) * 512 + c];
        // batched, unconditional (clamped) tap loads for the whole row
        const u16* vrow = vimg + (size_t)yy * 32 * CC;
        u16x4 vv[14];
#pragma unroll
        for (int sxi = 0; sxi < 14; sxi++) {
            int sx = x0 - 3 + sxi;
            int sxc = sx < 0 ? 0 : (sx > 31 ? 31 : sx);   // wave-uniform clamp
            vv[sxi] = *(const u16x4*)&vrow[(size_t)sxc * CC];
        }
        // convert (+branchless zero for out-of-range sx), then fma
#pragma unroll
        for (int sxi = 0; sxi < 14; sxi++) {
            int sx = x0 - 3 + sxi;
            bool xval = (sx >= 0) && (sx < 32);
            float vf[4];
#pragma unroll
            for (int j = 0; j < 4; j++) vf[j] = xval ? bf2f(vv[sxi][j]) : 0.f;
            int lo = sxi - 6 > 0 ? sxi - 6 : 0;
            int hi = sxi < 7 ? sxi : 7;
#pragma unroll
            for (int xi = 0; xi < 8; xi++) {
                if (xi < lo || xi > hi) continue;    // compile-time after unroll
                int dx = sxi - xi;
#pragma unroll
                for (int j = 0; j < 4; j++)
                    acc[xi][j] = fmaf(vf[j], wr[dx][j], acc[xi][j]);
            }
        }
    }

    const size_t rowbase = (size_t)(b * NN) + 1 + (size_t)y * 32 + x0;
    // batched epilogue loads
    u16x4 qv[8], av[8];
#pragma unroll
    for (int xi = 0; xi < 8; xi++) {
        size_t o = (rowbase + xi) * CC + c;
        qv[xi] = *(const u16x4*)&qbf[o];
        av[xi] = *(const u16x4*)&attbf[o];
    }
#pragma unroll
    for (int xi = 0; xi < 8; xi++) {
        size_t o = (rowbase + xi) * CC + c;
        u16x4 ov;
#pragma unroll
        for (int j = 0; j < 4; j++)
            ov[j] = f2bf(bf2f(av[xi][j]) + bf2f(qv[xi][j]) * acc[xi][j]);
        *(u16x4*)&attbf[o] = ov;
    }
}

// ---------------------------------------------------------------------------
extern "C" void kernel_launch(void* const* d_in, const int* in_sizes, int n_in,
                              void* d_out, int out_size, void* d_ws, size_t ws_size,
                              hipStream_t stream)
{
    const float* x     = (const float*)d_in[0];
    const float* Wqkv  = (const float*)d_in[1];
    const float* bqkv  = (const float*)d_in[2];
    const float* Wproj = (const float*)d_in[3];
    const float* bproj = (const float*)d_in[4];
    const float* ck3   = (const float*)d_in[5];
    const float* cb3   = (const float*)d_in[6];
    const float* ck5   = (const float*)d_in[7];
    const float* cb5   = (const float*)d_in[8];
    const float* ck7   = (const float*)d_in[9];
    const float* cb7   = (const float*)d_in[10];
    float* out = (float*)d_out;

    const size_t PLANE = (size_t)MP * CC;

    u16* xbf  = (u16*)d_ws;
    u16* qbf  = xbf + PLANE;
    u16* kbf  = qbf + PLANE;
    u16* vbf  = kbf + PLANE;
    u16* wqT  = vbf + PLANE;
    u16* wpT  = wqT + (size_t)1536 * 512;
    u16* ksvT = wpT + (size_t)512 * 512;           // 256*4096 bf16
    float* pmax   = (float*)(ksvT + (size_t)256 * 4096);
    float* psum   = pmax + 8 * BB * CC;
    float* colmax = psum + 8 * BB * CC;
    float* colsum = colmax + BB * CC;
    float* part   = colsum + BB * CC;              // 4 * 256 * 4096 f32
    float* w7     = part + (size_t)4 * 256 * 4096; // 49*512
    float* cbx    = w7 + 49 * 512;                 // 512
    u16* attbf = xbf;                              // alias (x dead after qkv)

    // 1) converts + conv-weight expansion
    convert_x_kernel<<<(int)(PLANE / 8 / 256), 256, 0, stream>>>(x, xbf);
    convert_wt_kernel<<<1536 * 64 / 256, 256, 0, stream>>>(Wqkv, wqT, 1536);
    convert_wt_kernel<<<512 * 64 / 256, 256, 0, stream>>>(Wproj, wpT, 512);
    prep_w7_kernel<<<98, 256, 0, stream>>>(ck3, cb3, ck5, cb5, ck7, cb7, w7, cbx);

    // 2) qkv GEMM -> bf16 q/k/v planes
    {
        int nwg = 12 * (MP / 128);   // 3096
        gemm_bf16_kernel<0, 1536, 12><<<nwg, 256, 0, stream>>>(xbf, wqT, bqkv, qbf, nwg);
    }
    // 3) softmax stats
    {
        dim3 grid(CC / 256, BB, 8);
        stats_part_kernel<<<grid, 256, 0, stream>>>(kbf, pmax, psum);
        stats_merge_kernel<<<BB * CC / 256, 256, 0, stream>>>(pmax, psum, colmax, colsum);
    }
    // 4) ksv partials + transpose-reduce (folds SCALE/colsum, emits bf16 B^T)
    {
        dim3 grid(BB * HH, 4);
        ksv_part_kernel<<<grid, 256, 0, stream>>>(kbf, vbf, colmax, part);
        ksv_reduceT_kernel<<<256 * 4096 / 4 / 256, 256, 0, stream>>>(part, colsum, ksvT);
    }
    // 5) factor att via MFMA -> attbf (all n, incl n=0)
    {
        dim3 grid((NN + 127) / 128, BB * HH);      // 9 x 256
        factor_mfma_kernel<<<grid, 256, 0, stream>>>(qbf, ksvT, attbf);
    }
    // 6) CRPE RMW (branchless batched loads)
    conv_rmw_kernel<<<BB * 32 * 2, 256, 0, stream>>>(vbf, qbf, w7, cbx, attbf);
    // 7) proj GEMM -> out
    {
        int nwg = 4 * (MP / 128);    // 1032
        gemm_bf16_kernel<1, 512, 4><<<nwg, 256, 0, stream>>>(attbf, wpT, bproj, out, nwg);
    }
}